// Round 1
// 601.313 us; speedup vs baseline: 1.0216x; 1.0216x over previous
//
#include <hip/hip_runtime.h>
#include <hip/hip_bf16.h>
#include <math.h>

// Problem constants
#define B_    32
#define CDD_  5
#define HIS_  100
#define S_    20
#define L_    3
#define F_    150
#define K_    18
#define RDIM_ 256
#define ROWE_ 9000           // S*L*F
#define NBC_  160            // B*CDD

typedef __attribute__((ext_vector_type(8))) short short8;
typedef __attribute__((ext_vector_type(4))) float f32x4;

// RNE float->bf16 (no NaN inputs here)
static __device__ __forceinline__ unsigned short f2bf(float x) {
  union { float f; unsigned u; } v; v.f = x;
  unsigned r = v.u + 0x7fffu + ((v.u >> 16) & 1u);
  return (unsigned short)(r >> 16);
}

// ---------------------------------------------------------------------------
// Kernel A: attention + stable top-K. grid=160 blocks x 256 threads.
// Also performs the conv-weight transposes (prep duty folded in) and
// zero-inits the score accumulator.
// ---------------------------------------------------------------------------
__global__ __launch_bounds__(256) void attn_topk_kernel(
    const int* __restrict__ cdd_id, const int* __restrict__ his_id,
    const float* __restrict__ repr, int* __restrict__ gid,
    float* __restrict__ score,
    const float* __restrict__ w1, const float* __restrict__ w2,
    float* __restrict__ w1t, float* __restrict__ w2t) {
  int bc = blockIdx.x;          // 0..159
  int b  = bc / CDD_;
  int tid = threadIdx.x, lane = tid & 63, wave = tid >> 6;

  // prep duty: weight transposes, distributed over the grid
  int gidx = bc * 256 + tid;
  if (gidx < 2592) {
    int oc = gidx / 81, j = gidx % 81;
    w1t[j * 32 + oc] = w1[gidx];
  } else if (gidx < 2592 + 13824) {
    int i2 = gidx - 2592;
    int oc = i2 / 864, r = i2 % 864;
    w2t[r * 16 + oc] = w2[i2];
  }

  __shared__ float cddv[RDIM_];
  __shared__ float sattn[128];
  int cid = cdd_id[bc];
  cddv[tid] = repr[(size_t)cid * RDIM_ + tid];
  if (tid < 28) sattn[100 + tid] = -INFINITY;
  __syncthreads();

  float4 cv = *(const float4*)(cddv + lane * 4);
  for (int h = wave; h < HIS_; h += 4) {
    const float4* row = (const float4*)(repr + (size_t)his_id[b * HIS_ + h] * RDIM_);
    float4 rv = row[lane];
    float p = cv.x * rv.x;
    p = fmaf(cv.y, rv.y, p);
    p = fmaf(cv.z, rv.z, p);
    p = fmaf(cv.w, rv.w, p);
    #pragma unroll
    for (int off = 32; off >= 1; off >>= 1) p += __shfl_xor(p, off);
    if (lane == 0) sattn[h] = p;
  }
  __syncthreads();

  if (wave == 0) {
    float v0 = sattn[lane], v1 = sattn[lane + 64];
    for (int k = 0; k < K_; k++) {
      float bv; int bi;
      if (v1 > v0) { bv = v1; bi = lane + 64; } else { bv = v0; bi = lane; }
      #pragma unroll
      for (int off = 32; off >= 1; off >>= 1) {
        float ov = __shfl_xor(bv, off);
        int   oi = __shfl_xor(bi, off);
        if (ov > bv || (ov == bv && oi < bi)) { bv = ov; bi = oi; }
      }
      if (lane == 0) gid[bc * K_ + k] = his_id[b * HIS_ + bi];
      if (bi == lane)      v0 = -INFINITY;
      if (bi == lane + 64) v1 = -INFINITY;
    }
  }
  if (tid == 0) score[bc] = 0.f;
}

// ---------------------------------------------------------------------------
// Kernel B: fusion einsum via bf16 MFMA. grid = 2880 blocks (b,c,k), 256 thr.
// Per l: C[20x20] = A[20x150] x B[20x150]^T, as 2x2 tiles of 16x16 with
// 5 K-steps of 32 (K padded 150->160, M/N padded 20->32).
// Changes this round:
//  - XCD-colocating swizzle: all 18 k-blocks of one bc on one XCD -> cdd row
//    fetched once per XCD L2 instead of ~8-18x.
//  - float4 (16B/lane) staging loads over the whole row; each float4 packs
//    into exactly two bf16x2 LDS words (f stays even at segment boundaries).
//  - zero-init only the K-pad columns (f 150..159). s-pad rows 20..31 stay
//    uninitialized: garbage there only reaches C rows/cols >= 20, which the
//    guarded store discards (C elements are independent dots).
// ---------------------------------------------------------------------------
__global__ __launch_bounds__(256) void fusion_kernel(
    const int* __restrict__ cdd_id, const int* __restrict__ gid,
    const float* __restrict__ emb, float* __restrict__ x1) {
  // XCD swizzle: 2880 blocks, 8 XCDs, 360 per XCD chunk (360 % 18 == 0 so
  // each chunk holds whole bc groups).
  int bck = (blockIdx.x & 7) * 360 + (blockIdx.x >> 3);
  int bc = bck / K_, k = bck % K_;
  __shared__ unsigned short a_sh[3 * 32 * 160];   // 30 KB
  __shared__ unsigned short b_sh[3 * 32 * 160];   // 30 KB
  int tid = threadIdx.x;

  unsigned* az = (unsigned*)a_sh;
  unsigned* bz = (unsigned*)b_sh;
  // zero only the K-pad (f2 index 75..79) for all 96 rows
  for (int i = tid; i < 480; i += 256) {
    int l = i / 160, r = i % 160;
    int srow = r / 5, j = r % 5;
    int idx = (l * 32 + srow) * 80 + 75 + j;
    az[idx] = 0u; bz[idx] = 0u;
  }

  const float* crow = emb + (size_t)cdd_id[bc] * ROWE_;
  const float* hrow = emb + (size_t)gid[bck] * ROWE_;
  // 16B/lane staging: 2250 float4 per row
  for (int p = tid; p < 2250; p += 256) {
    int e0 = p * 4;
    int s0 = e0 / 450, r0 = e0 % 450;
    int l0 = r0 / 150, f0 = r0 % 150;
    int e2 = e0 + 2;
    int s2 = e2 / 450, r2 = e2 % 450;
    int l2 = r2 / 150, f2 = r2 % 150;
    float4 cv = *(const float4*)(crow + e0);
    float4 hv = *(const float4*)(hrow + e0);
    int d0 = (l0 * 32 + s0) * 80 + (f0 >> 1);
    int d2 = (l2 * 32 + s2) * 80 + (f2 >> 1);
    az[d0] = (unsigned)f2bf(cv.x) | ((unsigned)f2bf(cv.y) << 16);
    az[d2] = (unsigned)f2bf(cv.z) | ((unsigned)f2bf(cv.w) << 16);
    bz[d0] = (unsigned)f2bf(hv.x) | ((unsigned)f2bf(hv.y) << 16);
    bz[d2] = (unsigned)f2bf(hv.z) | ((unsigned)f2bf(hv.w) << 16);
  }
  __syncthreads();

  int wave = tid >> 6, lane = tid & 63;
  int m15 = lane & 15, quad = lane >> 4;
  const float scale = 0.0816496580927726f;    // 1/sqrt(150)
  for (int j = wave; j < 12; j += 4) {        // j = l*4 + mt*2 + nt
    int l = j >> 2, mt = (j >> 1) & 1, nt = j & 1;
    f32x4 acc = {0.f, 0.f, 0.f, 0.f};
    int abase = (l * 32 + mt * 16 + m15) * 160 + quad * 8;
    int bbase = (l * 32 + nt * 16 + m15) * 160 + quad * 8;
    #pragma unroll
    for (int kb = 0; kb < 5; kb++) {
      short8 af = *(const short8*)(a_sh + abase + kb * 32);
      short8 bf = *(const short8*)(b_sh + bbase + kb * 32);
      acc = __builtin_amdgcn_mfma_f32_16x16x32_bf16(af, bf, acc, 0, 0, 0);
    }
    int t = nt * 16 + m15;
    if (t < 20) {
      size_t base = ((size_t)(bc * 3 + l) * K_ + k) * 400;
      #pragma unroll
      for (int reg = 0; reg < 4; reg++) {
        int s = mt * 16 + quad * 4 + reg;
        if (s < 20) x1[base + s * 20 + t] = acc[reg] * scale;
      }
    }
  }
}

// ---------------------------------------------------------------------------
// Kernel C: conv1(3->32) + bias + ReLU + maxpool, fused. grid = 960, 256 thr.
// Thread=position, acc[32] registers; inner loop = 1 LDS read broadcast into
// 32 FMAs with scalar-cached weights from w1t.
// ---------------------------------------------------------------------------
__global__ __launch_bounds__(256) void conv1_kernel(
    const float* __restrict__ x1, const float* __restrict__ w1t,
    const float* __restrict__ b1, float* __restrict__ p1) {
  int bid = blockIdx.x;
  int n = bid / 6, dp = bid % 6;
  __shared__ float tile[3 * 5 * 22 * 22];     // 7260 floats, padded input slab
  __shared__ unsigned pooled[32 * 36];        // 32 oc x (6x6)
  int tid = threadIdx.x;

  for (int i = tid; i < 7260; i += 256) {
    int c = i / 2420; int r = i % 2420;
    int dd = r / 484; r %= 484;
    int hh = r / 22, ww = r % 22;
    int d = dp * 3 + dd - 1, h = hh - 1, w = ww - 1;
    float v = 0.f;
    if (d >= 0 && d < 18 && h >= 0 && h < 20 && w >= 0 && w < 20)
      v = x1[((size_t)(n * 3 + c) * K_ + d) * 400 + h * 20 + w];
    tile[i] = v;
  }
  for (int i = tid; i < 1152; i += 256) pooled[i] = 0u;
  __syncthreads();

  for (int pos = tid; pos < 972; pos += 256) {
    int dl = pos / 324; int r = pos % 324;
    int h = r / 18, w = r % 18;
    float acc[32];
    #pragma unroll
    for (int oc = 0; oc < 32; oc++) acc[oc] = b1[oc];

    for (int c = 0; c < 3; c++) {
      const float* tc = tile + (c * 5 + dl) * 484 + h * 22 + w;
      const float* wc = w1t + c * 27 * 32;
      #pragma unroll
      for (int kd = 0; kd < 3; kd++)
        #pragma unroll
        for (int kh = 0; kh < 3; kh++)
          #pragma unroll
          for (int kw = 0; kw < 3; kw++) {
            float iv = tc[kd * 484 + kh * 22 + kw];
            const float* wp = wc + (kd * 9 + kh * 3 + kw) * 32;
            #pragma unroll
            for (int oc = 0; oc < 32; oc++) acc[oc] = fmaf(iv, wp[oc], acc[oc]);
          }
    }
    int pbase = (h / 3) * 6 + (w / 3);
    #pragma unroll
    for (int oc = 0; oc < 32; oc++)
      atomicMax(&pooled[oc * 36 + pbase], __float_as_uint(fmaxf(acc[oc], 0.f)));
  }
  __syncthreads();
  for (int i = tid; i < 1152; i += 256) {
    int oc = i / 36; int r = i % 36;
    p1[(size_t)(n * 32 + oc) * 216 + dp * 36 + r] = __uint_as_float(pooled[i]);
  }
}

// ---------------------------------------------------------------------------
// Kernel D: conv2(32->16) + bias + ReLU + maxpool + LTR dot. grid = 320.
// Padded LDS tile [32][8][8][8]; acc[8] registers; scalar-broadcast weights.
// One float atomicAdd per block into score[n].
// ---------------------------------------------------------------------------
__global__ __launch_bounds__(256) void conv2_kernel(
    const float* __restrict__ p1, const float* __restrict__ w2t,
    const float* __restrict__ b2, const float* __restrict__ lw,
    float* __restrict__ score) {
  int bid = blockIdx.x;
  int n = bid / 2, og = bid % 2;
  __shared__ float tile[32 * 8 * 8 * 8];   // 64KB padded: [c][d+1][h+1][w+1]
  __shared__ unsigned pooled[64];          // 8 oc x 8 pooled pos
  int tid = threadIdx.x;

  for (int i = tid; i < 32 * 512; i += 256) tile[i] = 0.f;
  if (tid < 64) pooled[tid] = 0u;
  __syncthreads();
  for (int i = tid; i < 32 * 216; i += 256) {
    int c = i / 216; int r = i % 216;
    int d = r / 36; r %= 36;
    int h = r / 6, w = r % 6;
    tile[c * 512 + (d + 1) * 64 + (h + 1) * 8 + (w + 1)] =
        p1[(size_t)n * 32 * 216 + i];
  }
  __syncthreads();

  if (tid < 216) {
    int d = tid / 36; int r = tid % 36;
    int h = r / 6, w = r % 6;
    float acc[8];
    #pragma unroll
    for (int oc = 0; oc < 8; oc++) acc[oc] = b2[og * 8 + oc];
    for (int c = 0; c < 32; c++) {
      const float* tc = tile + c * 512 + d * 64 + h * 8 + w;  // window origin
      const float* wc = w2t + c * 27 * 16 + og * 8;
      #pragma unroll
      for (int kd = 0; kd < 3; kd++)
        #pragma unroll
        for (int kh = 0; kh < 3; kh++)
          #pragma unroll
          for (int kw = 0; kw < 3; kw++) {
            float iv = tc[kd * 64 + kh * 8 + kw];
            const float* wp = wc + (kd * 9 + kh * 3 + kw) * 16;
            #pragma unroll
            for (int oc = 0; oc < 8; oc++) acc[oc] = fmaf(iv, wp[oc], acc[oc]);
          }
    }
    int pb = (d / 3) * 4 + (h / 3) * 2 + (w / 3);
    #pragma unroll
    for (int oc = 0; oc < 8; oc++)
      atomicMax(&pooled[oc * 8 + pb], __float_as_uint(fmaxf(acc[oc], 0.f)));
  }
  __syncthreads();

  if (tid < 64) {
    int oc = tid / 8, pb = tid % 8;
    float contrib = __uint_as_float(pooled[tid]) * lw[(og * 8 + oc) * 8 + pb];
    #pragma unroll
    for (int off = 32; off >= 1; off >>= 1) contrib += __shfl_xor(contrib, off);
    if (tid == 0) atomicAdd(&score[n], contrib);
  }
}

// ---------------------------------------------------------------------------
// Kernel E: +bias, log_softmax over the 5 candidates per batch row.
// ---------------------------------------------------------------------------
__global__ __launch_bounds__(64) void softmax_kernel(
    const float* __restrict__ score, const float* __restrict__ lb,
    float* __restrict__ out) {
  int b = threadIdx.x;
  if (b < B_) {
    float s[CDD_];
    float mx = -INFINITY;
    #pragma unroll
    for (int c = 0; c < CDD_; c++) {
      s[c] = score[b * CDD_ + c] + lb[0];
      mx = fmaxf(mx, s[c]);
    }
    float sum = 0.f;
    #pragma unroll
    for (int c = 0; c < CDD_; c++) sum += expf(s[c] - mx);
    float lse = mx + logf(sum);
    #pragma unroll
    for (int c = 0; c < CDD_; c++) out[b * CDD_ + c] = s[c] - lse;
  }
}

// ---------------------------------------------------------------------------
extern "C" void kernel_launch(void* const* d_in, const int* in_sizes, int n_in,
                              void* d_out, int out_size, void* d_ws, size_t ws_size,
                              hipStream_t stream) {
  const int*   cdd_id = (const int*)d_in[0];
  const int*   his_id = (const int*)d_in[1];
  const float* repr   = (const float*)d_in[2];
  const float* emb    = (const float*)d_in[3];
  const float* w1     = (const float*)d_in[4];
  const float* b1     = (const float*)d_in[5];
  const float* w2     = (const float*)d_in[6];
  const float* b2     = (const float*)d_in[7];
  const float* lw     = (const float*)d_in[8];
  const float* lb     = (const float*)d_in[9];
  float* out = (float*)d_out;

  // workspace layout (~18.3 MB)
  char* ws = (char*)d_ws;
  int*   gid   = (int*)ws;                               // 2880 ints
  float* score = (float*)(ws + 11520);                   // 160 floats
  float* x1    = (float*)(ws + 12160);                   // 3,456,000 floats
  float* p1    = (float*)(ws + 12160 + 13824000);        // 1,105,920 floats
  float* w1t   = (float*)(ws + 12160 + 13824000 + 4423680);        // 2592 f
  float* w2t   = (float*)(ws + 12160 + 13824000 + 4423680 + 10368); // 13824 f

  attn_topk_kernel<<<NBC_, 256, 0, stream>>>(cdd_id, his_id, repr, gid, score,
                                             w1, w2, w1t, w2t);
  fusion_kernel<<<NBC_ * K_, 256, 0, stream>>>(cdd_id, gid, emb, x1);
  conv1_kernel<<<NBC_ * 6, 256, 0, stream>>>(x1, w1t, b1, p1);
  conv2_kernel<<<NBC_ * 2, 256, 0, stream>>>(p1, w2t, b2, lw, score);
  softmax_kernel<<<1, 64, 0, stream>>>(score, lb, out);
}